// Round 11
// baseline (451.010 us; speedup 1.0000x reference)
//
#include <hip/hip_runtime.h>
#include <math.h>

// ----------------------------------------------------------------------------
// MultiHeadAttentionQuantum: 8-qubit RX/CNOT-ring circuit projections + MHA.
//
// Timing model (validated rounds 2-10): dur_us = harness fill (~167us, fixed)
//   + qproj3 (~71) + attn (~75) + qproj1 (~24).
//
// Round-13 (this round): EXACT round-8 base (337.0us best; qproj occupancy
//   pushes refuted: r4/r10 spill at 170-cap, r6/r9 relayout slower). One
//   change: attn __launch_bounds__(256,2) -> (256,4). attn runs at 88 VGPR
//   (round-2 counter) so 4 waves/SIMD fit easily; the old bound -- not
//   registers -- capped residency (Occupancy 19%). 2x resident waves = 2x
//   outstanding nt stores, attacking the diagnosed concurrency limit of the
//   268MB attn write stream (3.6 TB/s vs 6.4 fill ceiling).
//
// qsim (rounds 5+7, verified): amps packed as 32 f2 along local bit5
//   (wire 2): vr[m] = (amp m, amp m+32). Layer-1 RX folded into the product
//   state (RX(x)RX(th0)=RX(x+th0), no CNOT between embedding and layer 1).
//   L2 masks {C0,60,30,18,0C,06,03,C1}; pruned-WHT readout (full wv[32],
//   round-8 verified form).
//
// attn (rounds 3+10): lane owns j = t*256 + lane*4 + c; dense 1KB nt stores;
//   softmax without max-shift (|s|<=2 exactly); 8 rows/wave, grid 2048.
// ----------------------------------------------------------------------------

#define NSAMP 32768  // B*S = 32*1024

typedef float f2 __attribute__((ext_vector_type(2)));
typedef float f4 __attribute__((ext_vector_type(4)));

// DPP ctrl codes (gfx9/CDNA): quad_perm xor1/2/3, quad bcast j, row mirrors.
#define QX1 0xB1  // [1,0,3,2]
#define QX2 0x4E  // [2,3,0,1]
#define QX3 0x1B  // [3,2,1,0]
#define QB0 0x00
#define QB1 0x55
#define QB2 0xAA
#define QB3 0xFF
#define ROW_MIRROR 0x140       // lane ^ 15 within 16
#define ROW_HALF_MIRROR 0x141  // lane ^ 7 within 8

template <int CTRL>
__device__ __forceinline__ float dppf(float x) {
  int xi = __float_as_int(x);
  return __int_as_float(
      __builtin_amdgcn_update_dpp(xi, xi, CTRL, 0xF, 0xF, false));
}

template <int CTRL>
__device__ __forceinline__ f2 dpp2(f2 v) {
  f2 r;
  r.x = dppf<CTRL>(v.x);
  r.y = dppf<CTRL>(v.y);
  return r;
}

__device__ __forceinline__ f2 swap2(f2 v) {
  f2 r;
  r.x = v.y;
  r.y = v.x;
  return r;
}

#define F2FMA(a, b, c) __builtin_elementwise_fma((a), (b), (c))

// ---- packed gates: vr/vi are 32 x f2; halves = local bit5 (0 / 1) ----------

// Cross-lane RX, no local mask (0xC0).
template <int CTRL>
__device__ __forceinline__ void gq0(float c, float s, f2* vr, f2* vi) {
  const f2 c2 = {c, c}, s2 = {s, s};
#pragma unroll
  for (int m = 0; m < 32; ++m) {
    f2 pr = dpp2<CTRL>(vr[m]);
    f2 pi = dpp2<CTRL>(vi[m]);
    vr[m] = F2FMA(c2, vr[m], s2 * pi);
    vi[m] = F2FMA(c2, vi[m], -s2 * pr);
  }
}

// Cross-lane RX + local bit0 (0xC1).
template <int CTRL>
__device__ __forceinline__ void gq_l1(float c, float s, f2* vr, f2* vi) {
  const f2 c2 = {c, c}, s2 = {s, s};
#pragma unroll
  for (int m = 0; m < 32; m += 2) {
    f2 pr0 = dpp2<CTRL>(vr[m]), pi0 = dpp2<CTRL>(vi[m]);
    f2 pr1 = dpp2<CTRL>(vr[m + 1]), pi1 = dpp2<CTRL>(vi[m + 1]);
    vr[m] = F2FMA(c2, vr[m], s2 * pi1);
    vi[m] = F2FMA(c2, vi[m], -s2 * pr1);
    vr[m + 1] = F2FMA(c2, vr[m + 1], s2 * pi0);
    vi[m + 1] = F2FMA(c2, vi[m + 1], -s2 * pr0);
  }
}

// Cross-lane RX + local bit5 (0x60): partner is DPP of the other half.
template <int CTRL>
__device__ __forceinline__ void gq_l20(float c, float s, f2* vr, f2* vi) {
  const f2 c2 = {c, c}, s2 = {s, s};
#pragma unroll
  for (int m = 0; m < 32; ++m) {
    f2 pr = dpp2<CTRL>(vr[m]);
    f2 pi = dpp2<CTRL>(vi[m]);
    vr[m] = F2FMA(c2, vr[m], s2 * swap2(pi));
    vi[m] = F2FMA(c2, vi[m], -s2 * swap2(pr));
  }
}

// Intra-lane RX, mask within bits0..4 (both halves identical pattern).
template <int ML>
__device__ __forceinline__ void gl(float c, float s, f2* vr, f2* vi) {
  constexpr int HB = ML >= 16 ? 16 : ML >= 8 ? 8 : ML >= 4 ? 4
                     : ML >= 2 ? 2 : 1;
  const f2 c2 = {c, c}, s2 = {s, s};
#pragma unroll
  for (int m = 0; m < 32; ++m) {
    if (!(m & HB)) {
      const int p = m ^ ML;
      f2 a0r = vr[m], a0i = vi[m], a1r = vr[p], a1i = vi[p];
      vr[m] = F2FMA(c2, a0r, s2 * a1i);
      vi[m] = F2FMA(c2, a0i, -s2 * a1r);
      vr[p] = F2FMA(c2, a1r, s2 * a0i);
      vi[p] = F2FMA(c2, a1i, -s2 * a0r);
    }
  }
}

// Intra-lane RX, mask = bits4+5 (0x30): partner = other half of m^0x10.
__device__ __forceinline__ void gl30(float c, float s, f2* vr, f2* vi) {
  const f2 c2 = {c, c}, s2 = {s, s};
#pragma unroll
  for (int m = 0; m < 32; ++m) {
    if (!(m & 0x10)) {
      const int p = m ^ 0x10;
      f2 or0 = vr[m], oi0 = vi[m], or1 = vr[p], oi1 = vi[p];
      vr[m] = F2FMA(c2, or0, s2 * swap2(oi1));
      vi[m] = F2FMA(c2, oi0, -s2 * swap2(or1));
      vr[p] = F2FMA(c2, or1, s2 * swap2(oi0));
      vi[p] = F2FMA(c2, oi1, -s2 * swap2(or0));
    }
  }
}

// 2-stage signed quad WHT: returns, in quad-lane u, sum_q (-1)^<u,q> W_q.
__device__ __forceinline__ float quad_wht(float v, int qq) {
  float u = dppf<QX1>(v);
  v = (qq & 1) ? (u - v) : (v + u);
  u = dppf<QX2>(v);
  v = (qq & 2) ? (u - v) : (v + u);
  return v;
}

// in:  sample angle rows [samp][8]; wc/wsn: cos/sin of the layer-2 weight
// half-angles (LDS, idx 8..15); thw: 0.5*theta0_w (layer-1 fold, idx 0..7);
// out: [samp][8] expvals. Wave handles samples [sampBase, sampBase+16).
__device__ __forceinline__ void qsim_wave(const float* __restrict__ in,
                                          float* __restrict__ outp,
                                          int sampBase,
                                          const float* __restrict__ wc,
                                          const float* __restrict__ wsn,
                                          const float* __restrict__ thw) {
  const int lane = threadIdx.x & 63;
  const int qq = lane & 3;
  const int g = lane >> 2;
  const int samp = sampBase + g;

  // Input trig with layer-1 RX folded in: RX(x)RX(th0) = RX(x+th0), so the
  // product state uses half-angle 0.5*x_w + 0.5*th0_w. Lane qq computes
  // wires 2qq, 2qq+1; quad-broadcast all 8.
  const float2 xx = *(const float2*)(in + (size_t)samp * 8 + 2 * qq);
  float h0 = 0.5f * xx.x + thw[2 * qq];
  float h1 = 0.5f * xx.y + thw[2 * qq + 1];
  float c0 = cosf(h0), s0 = sinf(h0);
  float c1 = cosf(h1), s1 = sinf(h1);
  float cw[8], sw[8];
  cw[0] = dppf<QB0>(c0); cw[1] = dppf<QB0>(c1);
  sw[0] = dppf<QB0>(s0); sw[1] = dppf<QB0>(s1);
  cw[2] = dppf<QB1>(c0); cw[3] = dppf<QB1>(c1);
  sw[2] = dppf<QB1>(s0); sw[3] = dppf<QB1>(s1);
  cw[4] = dppf<QB2>(c0); cw[5] = dppf<QB2>(c1);
  sw[4] = dppf<QB2>(s0); sw[5] = dppf<QB2>(s1);
  cw[6] = dppf<QB3>(c0); cw[7] = dppf<QB3>(c1);
  sw[6] = dppf<QB3>(s0); sw[7] = dppf<QB3>(s1);

  // Product-state magnitudes over local bits 0..4 (scalar doubling),
  // then bit5 (wire 2, cw[2]/sw[2]) becomes the vector-half dimension.
  float mm[32];
  mm[0] = ((qq & 1) ? sw[1] : cw[1]) * ((qq & 2) ? sw[0] : cw[0]);
#pragma unroll
  for (int k = 0; k < 5; ++k) {
    const float cc = cw[7 - k], ss = sw[7 - k];
#pragma unroll
    for (int t = (1 << k) - 1; t >= 0; --t) {
      mm[t + (1 << k)] = mm[t] * ss;
      mm[t] = mm[t] * cc;
    }
  }

  // Phase (-i)^popcount(d): local part compile-time; half y has popc+1.
  f2 vr[32], vi[32];
  const int pq = __builtin_popcount(qq);
#pragma unroll
  for (int m = 0; m < 32; ++m) {
    const float mx = mm[m] * cw[2];
    const float my = mm[m] * sw[2];
    const int plx = __builtin_popcount(m) & 3;  // half y: plx+1 mod 4
    f2 r, i;
    if (plx == 0) { r.x = mx;    i.x = 0.0f;  r.y = 0.0f;  i.y = -my; }
    else if (plx == 1) { r.x = 0.0f; i.x = -mx; r.y = -my; i.y = 0.0f; }
    else if (plx == 2) { r.x = -mx; i.x = 0.0f; r.y = 0.0f; i.y = my; }
    else { r.x = 0.0f; i.x = mx;   r.y = my;   i.y = 0.0f; }
    vr[m] = r;
    vi[m] = i;
  }
  if (pq == 1) {
#pragma unroll
    for (int m = 0; m < 32; ++m) {
      f2 t = vr[m];
      vr[m] = vi[m];
      vi[m] = -t;
    }
  } else if (pq == 2) {
#pragma unroll
    for (int m = 0; m < 32; ++m) {
      vr[m] = -vr[m];
      vi[m] = -vi[m];
    }
  }

  // Layer-1 RX gates: FOLDED into the product state above.

  // Layer 2 RX (idx 8..15), masks B1*e_w = {C0,60,30,18,0C,06,03,C1}.
  gq0<QX3>(wc[8], wsn[8], vr, vi);      // 0xC0
  gq_l20<QX1>(wc[9], wsn[9], vr, vi);   // 0x60
  gl30(wc[10], wsn[10], vr, vi);        // 0x30
  gl<0x18>(wc[11], wsn[11], vr, vi);
  gl<0x0C>(wc[12], wsn[12], vr, vi);
  gl<0x06>(wc[13], wsn[13], vr, vi);
  gl<0x03>(wc[14], wsn[14], vr, vi);
  gq_l1<QX3>(wc[15], wsn[15], vr, vi);  // 0xC1

  // Readout (pruned WHT, round-8 verified form). Packed |amp|^2, 3-stage
  // WHT over bits0..2 per group g = m>>3 (bits3..4), signed g-accumulation,
  // then half-combine with u5 parity, then quad WHT over bits6..7.
  f2 wv[32];
#pragma unroll
  for (int m = 0; m < 32; ++m)
    wv[m] = F2FMA(vr[m], vr[m], vi[m] * vi[m]);
#pragma unroll
  for (int gi = 0; gi < 4; ++gi) {
#pragma unroll
    for (int k = 0; k < 3; ++k) {
#pragma unroll
      for (int j = 0; j < 8; ++j) {
        if (!(j & (1 << k))) {
          const int a = gi * 8 + j, b2 = a | (1 << k);
          f2 A = wv[a], B = wv[b2];
          wv[a] = A + B;
          wv[b2] = A - B;
        }
      }
    }
  }
  // g-sign sets: u2=1: [+,-,+,-]; u2=2: [+,+,-,-]; u2=3: [+,-,-,+].
  const f2 aA = (wv[5] + wv[13]) - (wv[21] + wv[29]);    // u2=2, ulo=5
  const f2 aBC = (wv[7] + wv[31]) - (wv[15] + wv[23]);   // u2=3, ulo=7
  const f2 aD = (wv[7] + wv[23]) - (wv[15] + wv[31]);    // u2=1, ulo=7
  const f2 aE = (wv[7] + wv[15]) - (wv[23] + wv[31]);    // u2=2, ulo=7
  const f2 aF = (wv[3] + wv[19]) - (wv[11] + wv[27]);    // u2=1, ulo=3
  const f2 aG = (wv[2] + wv[18]) - (wv[10] + wv[26]);    // u2=1, ulo=2
  const float accA = aA.x + aA.y;   // u5=0
  const float accB = aBC.x - aBC.y; // u5=1
  const float accC = aBC.x + aBC.y; // u5=0
  const float accD = aD.x - aD.y;   // u5=1
  const float accE = aE.x + aE.y;   // u5=0
  const float accF = aF.x - aF.y;   // u5=1
  const float accG = aG.x - aG.y;   // u5=1

  const float o15 = quad_wht(accA, qq);  // serves i0 (qq=3) and i6 (qq=1)
  const float o3F = quad_wht(accB, qq);
  const float o1F = quad_wht(accC, qq);
  const float o2F = quad_wht(accD, qq);
  const float o17 = quad_wht(accE, qq);
  const float o2B = quad_wht(accF, qq);
  const float o2A = quad_wht(accG, qq);

  float* orow = outp + (size_t)samp * 8;
  if (qq == 3) orow[0] = o15;
  if (qq == 2) {
    orow[1] = o3F;
    orow[3] = o2F;
    orow[5] = o2B;
    orow[7] = o2A;
  }
  if (qq == 1) {
    orow[2] = o1F;
    orow[4] = o17;
    orow[6] = o15;
  }
}

// Per-block weight trig into LDS (threads 0..31): cos/sin of all 16 weight
// half-angles plus raw half-angles of layer-1 weights (for the fold).
__device__ __forceinline__ void weight_trig(const float* __restrict__ w,
                                            float* __restrict__ tc,
                                            float* __restrict__ tsn,
                                            float* __restrict__ thw) {
  if (threadIdx.x < 32) {
    const int a = threadIdx.x & 15;
    const float half = 0.5f * w[a];
    if (threadIdx.x < 16) {
      tc[a] = cosf(half);
      if (a < 8) thw[a] = half;
    } else {
      tsn[a] = sinf(half);
    }
  }
  __syncthreads();
}

__global__ __launch_bounds__(256, 2) void mhaq_qproj3_kernel(
    const float* __restrict__ q, const float* __restrict__ k,
    const float* __restrict__ v, const float* __restrict__ wq,
    const float* __restrict__ wk, const float* __restrict__ wv,
    float* __restrict__ qp, float* __restrict__ kp, float* __restrict__ vp) {
  __shared__ float tc[16], tsn[16], thw[8];
  const int wg = blockIdx.x * 4 + (threadIdx.x >> 6);  // 0..6143
  const int proj = wg >> 11;  // 2048 waves per projection; block-uniform
  const float* wsel = proj == 0 ? wq : proj == 1 ? wk : wv;
  weight_trig(wsel, tc, tsn, thw);
  const float* in = proj == 0 ? q : proj == 1 ? k : v;
  float* op = proj == 0 ? qp : proj == 1 ? kp : vp;
  qsim_wave(in, op, (wg & 2047) * 16, tc, tsn, thw);
}

__global__ __launch_bounds__(256, 2) void mhaq_qproj1_kernel(
    const float* __restrict__ ctx, const float* __restrict__ wd,
    float* __restrict__ outp) {
  __shared__ float tc[16], tsn[16], thw[8];
  weight_trig(wd, tc, tsn, thw);
  const int wg = blockIdx.x * 4 + (threadIdx.x >> 6);  // 0..2047
  qsim_wave(ctx, outp, wg * 16, tc, tsn, thw);
}

// Full-wave reductions: quad DPP + row mirrors + 2 shfl stages (only DS use).
__device__ __forceinline__ float wred_sum(float v) {
  v += dppf<QX1>(v);
  v += dppf<QX2>(v);
  v += dppf<ROW_HALF_MIRROR>(v);  // xor7 == xor4 after quad-uniform
  v += dppf<ROW_MIRROR>(v);       // xor15 == xor8 after 8-uniform
  v += __shfl_xor(v, 16, 64);
  v += __shfl_xor(v, 32, 64);
  return v;
}

// Attention: one wave per (b,h, 8-row chunk); K/V head slice in VGPRs.
// Lane owns j = t*256 + lane*4 + c (t,c in 0..3) so the attn-row store for
// each t is one dense, aligned 1 KB block per wave instruction (full-line
// HBM writes, nontemporal). Softmax WITHOUT max-shift: scores exactly
// bounded |s| <= 2 (q,k in [-1,1]^4 expvals, scale 0.5) -- identical
// softmax in fp32. Round-13: (256,4) -- 88 VGPR fits 4 waves/SIMD; the old
// (256,2) bound, not registers, was capping write concurrency.
__global__ __launch_bounds__(256, 4) void mhaq_attn_kernel(
    const float* __restrict__ qp, const float* __restrict__ kp,
    const float* __restrict__ vp, float* __restrict__ ctx,
    float* __restrict__ attn) {
  const int wg = blockIdx.x * 4 + (threadIdx.x >> 6);  // 0..8191
  const int bh = wg >> 7;      // 64 (b,h) pairs, 128 chunks each
  const int chunk = wg & 127;  // 8 rows per chunk
  const int b = bh >> 1, h = bh & 1;
  const int lane = threadIdx.x & 63;

  float4 kreg[16], vreg[16];
  const float* kbase = kp + (size_t)b * 1024 * 8 + h * 4;
  const float* vbase = vp + (size_t)b * 1024 * 8 + h * 4;
#pragma unroll
  for (int t = 0; t < 4; ++t) {
#pragma unroll
    for (int c = 0; c < 4; ++c) {
      const size_t j = (size_t)t * 256 + lane * 4 + c;
      kreg[t * 4 + c] = *(const float4*)(kbase + j * 8);
      vreg[t * 4 + c] = *(const float4*)(vbase + j * 8);
    }
  }

  for (int r = 0; r < 8; ++r) {
    const int i = chunk * 8 + r;
    const float4 qv = *(const float4*)(qp + ((size_t)b * 1024 + i) * 8 + h * 4);
    float e[16];
    float sum = 0.0f;
#pragma unroll
    for (int t = 0; t < 16; ++t) {
      float s = qv.x * kreg[t].x + qv.y * kreg[t].y + qv.z * kreg[t].z +
                qv.w * kreg[t].w;
      e[t] = __expf(s * 0.5f);  // 1/sqrt(D), D=4; no max-shift needed
      sum += e[t];
    }
    sum = wred_sum(sum);
    const float rinv = 1.0f / sum;

    float a0 = 0.f, a1 = 0.f, a2 = 0.f, a3 = 0.f;
    float* arow = attn + ((size_t)(bh * 1024 + i)) * 1024;
#pragma unroll
    for (int t = 0; t < 4; ++t) {
      float p0 = e[4 * t] * rinv, p1 = e[4 * t + 1] * rinv,
            p2 = e[4 * t + 2] * rinv, p3 = e[4 * t + 3] * rinv;
      // Dense nontemporal store: 64 lanes x float4 = contiguous 1 KB block.
      f4 pv = {p0, p1, p2, p3};
      __builtin_nontemporal_store(pv, (f4*)(arow + t * 256 + lane * 4));
      a0 = fmaf(p0, vreg[4 * t].x, a0);
      a1 = fmaf(p0, vreg[4 * t].y, a1);
      a2 = fmaf(p0, vreg[4 * t].z, a2);
      a3 = fmaf(p0, vreg[4 * t].w, a3);
      a0 = fmaf(p1, vreg[4 * t + 1].x, a0);
      a1 = fmaf(p1, vreg[4 * t + 1].y, a1);
      a2 = fmaf(p1, vreg[4 * t + 1].z, a2);
      a3 = fmaf(p1, vreg[4 * t + 1].w, a3);
      a0 = fmaf(p2, vreg[4 * t + 2].x, a0);
      a1 = fmaf(p2, vreg[4 * t + 2].y, a1);
      a2 = fmaf(p2, vreg[4 * t + 2].z, a2);
      a3 = fmaf(p2, vreg[4 * t + 2].w, a3);
      a0 = fmaf(p3, vreg[4 * t + 3].x, a0);
      a1 = fmaf(p3, vreg[4 * t + 3].y, a1);
      a2 = fmaf(p3, vreg[4 * t + 3].z, a2);
      a3 = fmaf(p3, vreg[4 * t + 3].w, a3);
    }
    a0 = wred_sum(a0);
    a1 = wred_sum(a1);
    a2 = wred_sum(a2);
    a3 = wred_sum(a3);
    if (lane == 0)
      *(float4*)(ctx + ((size_t)b * 1024 + i) * 8 + h * 4) =
          make_float4(a0, a1, a2, a3);
  }
}

extern "C" void kernel_launch(void* const* d_in, const int* in_sizes, int n_in,
                              void* d_out, int out_size, void* d_ws,
                              size_t ws_size, hipStream_t stream) {
  (void)in_sizes; (void)n_in; (void)out_size; (void)ws_size;
  const float* q = (const float*)d_in[0];
  const float* k = (const float*)d_in[1];
  const float* v = (const float*)d_in[2];
  const float* wq = (const float*)d_in[3];
  const float* wk = (const float*)d_in[4];
  const float* wv = (const float*)d_in[5];
  const float* wd = (const float*)d_in[6];
  float* outp = (float*)d_out;  // [0, 262144): out; then attn (B,H,S,S)
  float* attn = outp + 262144;

  float* wsf = (float*)d_ws;
  float* qp = wsf;
  float* kp = qp + (size_t)NSAMP * 8;
  float* vp = kp + (size_t)NSAMP * 8;
  float* ctx = vp + (size_t)NSAMP * 8;  // concat layout [b,s,h*4+d]

  hipLaunchKernelGGL(mhaq_qproj3_kernel, dim3(1536), dim3(256), 0, stream, q,
                     k, v, wq, wk, wv, qp, kp, vp);
  hipLaunchKernelGGL(mhaq_attn_kernel, dim3(2048), dim3(256), 0, stream, qp,
                     kp, vp, ctx, attn);
  hipLaunchKernelGGL(mhaq_qproj1_kernel, dim3(512), dim3(256), 0, stream, ctx,
                     wd, outp);
}

// Round 12
// 335.591 us; speedup vs baseline: 1.3439x; 1.3439x over previous
//
#include <hip/hip_runtime.h>
#include <math.h>

// ----------------------------------------------------------------------------
// MultiHeadAttentionQuantum: 8-qubit RX/CNOT-ring circuit projections + MHA.
//
// Timing model (validated rounds 2-11): dur_us = harness fill (~167us, fixed)
//   + qproj3 (~71) + attn (~75) + qproj1 (~24).
//
// Round-14 (this round): round-8 base (337.0us best). Round-11's (256,4) on
//   attn CAPPED VGPR at 64 -> kreg/vreg (128 regs) spilled to scratch
//   (FETCH_SIZE 8.7MB -> 340MB, attn 193us). LESSON: attn needs full-alloc
//   2 waves/SIMD; never bound below ~200 VGPR. But its 38%-occupancy run
//   still managed only 3.8 TB/s -> waves don't fix the write rate; the
//   per-row serial chain (score->exp->wred_sum->rinv->store) does. So:
//   ONE change vs round 8 -- attn processes 2 ROWS PER ITERATION with
//   independent register sets: 2x ILP inside the ~30-op DPP reduction
//   chains, 2x outstanding nt stores between reductions. Est. peak ~190
//   VGPR, still (256,2).
//
// qsim (rounds 5+7, verified): amps packed as 32 f2 along local bit5
//   (wire 2). Layer-1 RX folded into the product state (RX(x)RX(th0) =
//   RX(x+th0)). L2 masks {C0,60,30,18,0C,06,03,C1}; pruned-WHT readout.
//
// attn (rounds 3+10): lane owns j = t*256 + lane*4 + c; dense 1KB nt
//   stores; softmax without max-shift (|s|<=2 exactly); 8 rows/wave.
// ----------------------------------------------------------------------------

#define NSAMP 32768  // B*S = 32*1024

typedef float f2 __attribute__((ext_vector_type(2)));
typedef float f4 __attribute__((ext_vector_type(4)));

// DPP ctrl codes (gfx9/CDNA): quad_perm xor1/2/3, quad bcast j, row mirrors.
#define QX1 0xB1  // [1,0,3,2]
#define QX2 0x4E  // [2,3,0,1]
#define QX3 0x1B  // [3,2,1,0]
#define QB0 0x00
#define QB1 0x55
#define QB2 0xAA
#define QB3 0xFF
#define ROW_MIRROR 0x140       // lane ^ 15 within 16
#define ROW_HALF_MIRROR 0x141  // lane ^ 7 within 8

template <int CTRL>
__device__ __forceinline__ float dppf(float x) {
  int xi = __float_as_int(x);
  return __int_as_float(
      __builtin_amdgcn_update_dpp(xi, xi, CTRL, 0xF, 0xF, false));
}

template <int CTRL>
__device__ __forceinline__ f2 dpp2(f2 v) {
  f2 r;
  r.x = dppf<CTRL>(v.x);
  r.y = dppf<CTRL>(v.y);
  return r;
}

__device__ __forceinline__ f2 swap2(f2 v) {
  f2 r;
  r.x = v.y;
  r.y = v.x;
  return r;
}

#define F2FMA(a, b, c) __builtin_elementwise_fma((a), (b), (c))

// ---- packed gates: vr/vi are 32 x f2; halves = local bit5 (0 / 1) ----------

// Cross-lane RX, no local mask (0xC0).
template <int CTRL>
__device__ __forceinline__ void gq0(float c, float s, f2* vr, f2* vi) {
  const f2 c2 = {c, c}, s2 = {s, s};
#pragma unroll
  for (int m = 0; m < 32; ++m) {
    f2 pr = dpp2<CTRL>(vr[m]);
    f2 pi = dpp2<CTRL>(vi[m]);
    vr[m] = F2FMA(c2, vr[m], s2 * pi);
    vi[m] = F2FMA(c2, vi[m], -s2 * pr);
  }
}

// Cross-lane RX + local bit0 (0xC1).
template <int CTRL>
__device__ __forceinline__ void gq_l1(float c, float s, f2* vr, f2* vi) {
  const f2 c2 = {c, c}, s2 = {s, s};
#pragma unroll
  for (int m = 0; m < 32; m += 2) {
    f2 pr0 = dpp2<CTRL>(vr[m]), pi0 = dpp2<CTRL>(vi[m]);
    f2 pr1 = dpp2<CTRL>(vr[m + 1]), pi1 = dpp2<CTRL>(vi[m + 1]);
    vr[m] = F2FMA(c2, vr[m], s2 * pi1);
    vi[m] = F2FMA(c2, vi[m], -s2 * pr1);
    vr[m + 1] = F2FMA(c2, vr[m + 1], s2 * pi0);
    vi[m + 1] = F2FMA(c2, vi[m + 1], -s2 * pr0);
  }
}

// Cross-lane RX + local bit5 (0x60): partner is DPP of the other half.
template <int CTRL>
__device__ __forceinline__ void gq_l20(float c, float s, f2* vr, f2* vi) {
  const f2 c2 = {c, c}, s2 = {s, s};
#pragma unroll
  for (int m = 0; m < 32; ++m) {
    f2 pr = dpp2<CTRL>(vr[m]);
    f2 pi = dpp2<CTRL>(vi[m]);
    vr[m] = F2FMA(c2, vr[m], s2 * swap2(pi));
    vi[m] = F2FMA(c2, vi[m], -s2 * swap2(pr));
  }
}

// Intra-lane RX, mask within bits0..4 (both halves identical pattern).
template <int ML>
__device__ __forceinline__ void gl(float c, float s, f2* vr, f2* vi) {
  constexpr int HB = ML >= 16 ? 16 : ML >= 8 ? 8 : ML >= 4 ? 4
                     : ML >= 2 ? 2 : 1;
  const f2 c2 = {c, c}, s2 = {s, s};
#pragma unroll
  for (int m = 0; m < 32; ++m) {
    if (!(m & HB)) {
      const int p = m ^ ML;
      f2 a0r = vr[m], a0i = vi[m], a1r = vr[p], a1i = vi[p];
      vr[m] = F2FMA(c2, a0r, s2 * a1i);
      vi[m] = F2FMA(c2, a0i, -s2 * a1r);
      vr[p] = F2FMA(c2, a1r, s2 * a0i);
      vi[p] = F2FMA(c2, a1i, -s2 * a0r);
    }
  }
}

// Intra-lane RX, mask = bits4+5 (0x30): partner = other half of m^0x10.
__device__ __forceinline__ void gl30(float c, float s, f2* vr, f2* vi) {
  const f2 c2 = {c, c}, s2 = {s, s};
#pragma unroll
  for (int m = 0; m < 32; ++m) {
    if (!(m & 0x10)) {
      const int p = m ^ 0x10;
      f2 or0 = vr[m], oi0 = vi[m], or1 = vr[p], oi1 = vi[p];
      vr[m] = F2FMA(c2, or0, s2 * swap2(oi1));
      vi[m] = F2FMA(c2, oi0, -s2 * swap2(or1));
      vr[p] = F2FMA(c2, or1, s2 * swap2(oi0));
      vi[p] = F2FMA(c2, oi1, -s2 * swap2(or0));
    }
  }
}

// 2-stage signed quad WHT: returns, in quad-lane u, sum_q (-1)^<u,q> W_q.
__device__ __forceinline__ float quad_wht(float v, int qq) {
  float u = dppf<QX1>(v);
  v = (qq & 1) ? (u - v) : (v + u);
  u = dppf<QX2>(v);
  v = (qq & 2) ? (u - v) : (v + u);
  return v;
}

// in:  sample angle rows [samp][8]; wc/wsn: cos/sin of the layer-2 weight
// half-angles (LDS, idx 8..15); thw: 0.5*theta0_w (layer-1 fold, idx 0..7);
// out: [samp][8] expvals. Wave handles samples [sampBase, sampBase+16).
__device__ __forceinline__ void qsim_wave(const float* __restrict__ in,
                                          float* __restrict__ outp,
                                          int sampBase,
                                          const float* __restrict__ wc,
                                          const float* __restrict__ wsn,
                                          const float* __restrict__ thw) {
  const int lane = threadIdx.x & 63;
  const int qq = lane & 3;
  const int g = lane >> 2;
  const int samp = sampBase + g;

  // Input trig with layer-1 RX folded in: RX(x)RX(th0) = RX(x+th0), so the
  // product state uses half-angle 0.5*x_w + 0.5*th0_w. Lane qq computes
  // wires 2qq, 2qq+1; quad-broadcast all 8.
  const float2 xx = *(const float2*)(in + (size_t)samp * 8 + 2 * qq);
  float h0 = 0.5f * xx.x + thw[2 * qq];
  float h1 = 0.5f * xx.y + thw[2 * qq + 1];
  float c0 = cosf(h0), s0 = sinf(h0);
  float c1 = cosf(h1), s1 = sinf(h1);
  float cw[8], sw[8];
  cw[0] = dppf<QB0>(c0); cw[1] = dppf<QB0>(c1);
  sw[0] = dppf<QB0>(s0); sw[1] = dppf<QB0>(s1);
  cw[2] = dppf<QB1>(c0); cw[3] = dppf<QB1>(c1);
  sw[2] = dppf<QB1>(s0); sw[3] = dppf<QB1>(s1);
  cw[4] = dppf<QB2>(c0); cw[5] = dppf<QB2>(c1);
  sw[4] = dppf<QB2>(s0); sw[5] = dppf<QB2>(s1);
  cw[6] = dppf<QB3>(c0); cw[7] = dppf<QB3>(c1);
  sw[6] = dppf<QB3>(s0); sw[7] = dppf<QB3>(s1);

  // Product-state magnitudes over local bits 0..4 (scalar doubling),
  // then bit5 (wire 2, cw[2]/sw[2]) becomes the vector-half dimension.
  float mm[32];
  mm[0] = ((qq & 1) ? sw[1] : cw[1]) * ((qq & 2) ? sw[0] : cw[0]);
#pragma unroll
  for (int k = 0; k < 5; ++k) {
    const float cc = cw[7 - k], ss = sw[7 - k];
#pragma unroll
    for (int t = (1 << k) - 1; t >= 0; --t) {
      mm[t + (1 << k)] = mm[t] * ss;
      mm[t] = mm[t] * cc;
    }
  }

  // Phase (-i)^popcount(d): local part compile-time; half y has popc+1.
  f2 vr[32], vi[32];
  const int pq = __builtin_popcount(qq);
#pragma unroll
  for (int m = 0; m < 32; ++m) {
    const float mx = mm[m] * cw[2];
    const float my = mm[m] * sw[2];
    const int plx = __builtin_popcount(m) & 3;  // half y: plx+1 mod 4
    f2 r, i;
    if (plx == 0) { r.x = mx;    i.x = 0.0f;  r.y = 0.0f;  i.y = -my; }
    else if (plx == 1) { r.x = 0.0f; i.x = -mx; r.y = -my; i.y = 0.0f; }
    else if (plx == 2) { r.x = -mx; i.x = 0.0f; r.y = 0.0f; i.y = my; }
    else { r.x = 0.0f; i.x = mx;   r.y = my;   i.y = 0.0f; }
    vr[m] = r;
    vi[m] = i;
  }
  if (pq == 1) {
#pragma unroll
    for (int m = 0; m < 32; ++m) {
      f2 t = vr[m];
      vr[m] = vi[m];
      vi[m] = -t;
    }
  } else if (pq == 2) {
#pragma unroll
    for (int m = 0; m < 32; ++m) {
      vr[m] = -vr[m];
      vi[m] = -vi[m];
    }
  }

  // Layer-1 RX gates: FOLDED into the product state above.

  // Layer 2 RX (idx 8..15), masks B1*e_w = {C0,60,30,18,0C,06,03,C1}.
  gq0<QX3>(wc[8], wsn[8], vr, vi);      // 0xC0
  gq_l20<QX1>(wc[9], wsn[9], vr, vi);   // 0x60
  gl30(wc[10], wsn[10], vr, vi);        // 0x30
  gl<0x18>(wc[11], wsn[11], vr, vi);
  gl<0x0C>(wc[12], wsn[12], vr, vi);
  gl<0x06>(wc[13], wsn[13], vr, vi);
  gl<0x03>(wc[14], wsn[14], vr, vi);
  gq_l1<QX3>(wc[15], wsn[15], vr, vi);  // 0xC1

  // Readout (pruned WHT, round-8 verified form). Packed |amp|^2, 3-stage
  // WHT over bits0..2 per group g = m>>3 (bits3..4), signed g-accumulation,
  // then half-combine with u5 parity, then quad WHT over bits6..7.
  f2 wv[32];
#pragma unroll
  for (int m = 0; m < 32; ++m)
    wv[m] = F2FMA(vr[m], vr[m], vi[m] * vi[m]);
#pragma unroll
  for (int gi = 0; gi < 4; ++gi) {
#pragma unroll
    for (int k = 0; k < 3; ++k) {
#pragma unroll
      for (int j = 0; j < 8; ++j) {
        if (!(j & (1 << k))) {
          const int a = gi * 8 + j, b2 = a | (1 << k);
          f2 A = wv[a], B = wv[b2];
          wv[a] = A + B;
          wv[b2] = A - B;
        }
      }
    }
  }
  // g-sign sets: u2=1: [+,-,+,-]; u2=2: [+,+,-,-]; u2=3: [+,-,-,+].
  const f2 aA = (wv[5] + wv[13]) - (wv[21] + wv[29]);    // u2=2, ulo=5
  const f2 aBC = (wv[7] + wv[31]) - (wv[15] + wv[23]);   // u2=3, ulo=7
  const f2 aD = (wv[7] + wv[23]) - (wv[15] + wv[31]);    // u2=1, ulo=7
  const f2 aE = (wv[7] + wv[15]) - (wv[23] + wv[31]);    // u2=2, ulo=7
  const f2 aF = (wv[3] + wv[19]) - (wv[11] + wv[27]);    // u2=1, ulo=3
  const f2 aG = (wv[2] + wv[18]) - (wv[10] + wv[26]);    // u2=1, ulo=2
  const float accA = aA.x + aA.y;   // u5=0
  const float accB = aBC.x - aBC.y; // u5=1
  const float accC = aBC.x + aBC.y; // u5=0
  const float accD = aD.x - aD.y;   // u5=1
  const float accE = aE.x + aE.y;   // u5=0
  const float accF = aF.x - aF.y;   // u5=1
  const float accG = aG.x - aG.y;   // u5=1

  const float o15 = quad_wht(accA, qq);  // serves i0 (qq=3) and i6 (qq=1)
  const float o3F = quad_wht(accB, qq);
  const float o1F = quad_wht(accC, qq);
  const float o2F = quad_wht(accD, qq);
  const float o17 = quad_wht(accE, qq);
  const float o2B = quad_wht(accF, qq);
  const float o2A = quad_wht(accG, qq);

  float* orow = outp + (size_t)samp * 8;
  if (qq == 3) orow[0] = o15;
  if (qq == 2) {
    orow[1] = o3F;
    orow[3] = o2F;
    orow[5] = o2B;
    orow[7] = o2A;
  }
  if (qq == 1) {
    orow[2] = o1F;
    orow[4] = o17;
    orow[6] = o15;
  }
}

// Per-block weight trig into LDS (threads 0..31): cos/sin of all 16 weight
// half-angles plus raw half-angles of layer-1 weights (for the fold).
__device__ __forceinline__ void weight_trig(const float* __restrict__ w,
                                            float* __restrict__ tc,
                                            float* __restrict__ tsn,
                                            float* __restrict__ thw) {
  if (threadIdx.x < 32) {
    const int a = threadIdx.x & 15;
    const float half = 0.5f * w[a];
    if (threadIdx.x < 16) {
      tc[a] = cosf(half);
      if (a < 8) thw[a] = half;
    } else {
      tsn[a] = sinf(half);
    }
  }
  __syncthreads();
}

__global__ __launch_bounds__(256, 2) void mhaq_qproj3_kernel(
    const float* __restrict__ q, const float* __restrict__ k,
    const float* __restrict__ v, const float* __restrict__ wq,
    const float* __restrict__ wk, const float* __restrict__ wv,
    float* __restrict__ qp, float* __restrict__ kp, float* __restrict__ vp) {
  __shared__ float tc[16], tsn[16], thw[8];
  const int wg = blockIdx.x * 4 + (threadIdx.x >> 6);  // 0..6143
  const int proj = wg >> 11;  // 2048 waves per projection; block-uniform
  const float* wsel = proj == 0 ? wq : proj == 1 ? wk : wv;
  weight_trig(wsel, tc, tsn, thw);
  const float* in = proj == 0 ? q : proj == 1 ? k : v;
  float* op = proj == 0 ? qp : proj == 1 ? kp : vp;
  qsim_wave(in, op, (wg & 2047) * 16, tc, tsn, thw);
}

__global__ __launch_bounds__(256, 2) void mhaq_qproj1_kernel(
    const float* __restrict__ ctx, const float* __restrict__ wd,
    float* __restrict__ outp) {
  __shared__ float tc[16], tsn[16], thw[8];
  weight_trig(wd, tc, tsn, thw);
  const int wg = blockIdx.x * 4 + (threadIdx.x >> 6);  // 0..2047
  qsim_wave(ctx, outp, wg * 16, tc, tsn, thw);
}

// Full-wave reductions: quad DPP + row mirrors + 2 shfl stages (only DS use).
__device__ __forceinline__ float wred_sum(float v) {
  v += dppf<QX1>(v);
  v += dppf<QX2>(v);
  v += dppf<ROW_HALF_MIRROR>(v);  // xor7 == xor4 after quad-uniform
  v += dppf<ROW_MIRROR>(v);       // xor15 == xor8 after 8-uniform
  v += __shfl_xor(v, 16, 64);
  v += __shfl_xor(v, 32, 64);
  return v;
}

// Attention: one wave per (b,h, 8-row chunk); K/V head slice in VGPRs.
// Lane owns j = t*256 + lane*4 + c (t,c in 0..3): each attn-row store is
// one dense, aligned 1 KB nontemporal block per wave instruction. Softmax
// WITHOUT max-shift (|s| <= 2 exactly). Round-14: TWO rows per iteration
// with independent register sets -- 2x ILP in the DPP reduction chains and
// 2x outstanding nt stores. Full-alloc (256,2): do NOT cap VGPR below ~200
// (round-11 lesson: (256,4) capped at 64 -> K/V spilled, 340MB scratch).
__global__ __launch_bounds__(256, 2) void mhaq_attn_kernel(
    const float* __restrict__ qp, const float* __restrict__ kp,
    const float* __restrict__ vp, float* __restrict__ ctx,
    float* __restrict__ attn) {
  const int wg = blockIdx.x * 4 + (threadIdx.x >> 6);  // 0..8191
  const int bh = wg >> 7;      // 64 (b,h) pairs, 128 chunks each
  const int chunk = wg & 127;  // 8 rows per chunk
  const int b = bh >> 1, h = bh & 1;
  const int lane = threadIdx.x & 63;

  float4 kreg[16], vreg[16];
  const float* kbase = kp + (size_t)b * 1024 * 8 + h * 4;
  const float* vbase = vp + (size_t)b * 1024 * 8 + h * 4;
#pragma unroll
  for (int t = 0; t < 4; ++t) {
#pragma unroll
    for (int c = 0; c < 4; ++c) {
      const size_t j = (size_t)t * 256 + lane * 4 + c;
      kreg[t * 4 + c] = *(const float4*)(kbase + j * 8);
      vreg[t * 4 + c] = *(const float4*)(vbase + j * 8);
    }
  }

  for (int r = 0; r < 8; r += 2) {
    const int i0 = chunk * 8 + r;
    const int i1 = i0 + 1;
    const float4 qv0 =
        *(const float4*)(qp + ((size_t)b * 1024 + i0) * 8 + h * 4);
    const float4 qv1 =
        *(const float4*)(qp + ((size_t)b * 1024 + i1) * 8 + h * 4);
    float e0[16], e1[16];
    float sum0 = 0.0f, sum1 = 0.0f;
#pragma unroll
    for (int t = 0; t < 16; ++t) {
      float s0 = qv0.x * kreg[t].x + qv0.y * kreg[t].y + qv0.z * kreg[t].z +
                 qv0.w * kreg[t].w;
      float s1 = qv1.x * kreg[t].x + qv1.y * kreg[t].y + qv1.z * kreg[t].z +
                 qv1.w * kreg[t].w;
      e0[t] = __expf(s0 * 0.5f);  // 1/sqrt(D), D=4; no max-shift needed
      e1[t] = __expf(s1 * 0.5f);
      sum0 += e0[t];
      sum1 += e1[t];
    }
    sum0 = wred_sum(sum0);
    sum1 = wred_sum(sum1);
    const float rinv0 = 1.0f / sum0;
    const float rinv1 = 1.0f / sum1;

    float a00 = 0.f, a01 = 0.f, a02 = 0.f, a03 = 0.f;
    float a10 = 0.f, a11 = 0.f, a12 = 0.f, a13 = 0.f;
    float* arow0 = attn + ((size_t)(bh * 1024 + i0)) * 1024;
    float* arow1 = attn + ((size_t)(bh * 1024 + i1)) * 1024;
#pragma unroll
    for (int t = 0; t < 4; ++t) {
#pragma unroll
      for (int c = 0; c < 4; ++c) {
        const int u = 4 * t + c;
        e0[u] *= rinv0;
        e1[u] *= rinv1;
      }
      f4 pv0 = {e0[4 * t], e0[4 * t + 1], e0[4 * t + 2], e0[4 * t + 3]};
      f4 pv1 = {e1[4 * t], e1[4 * t + 1], e1[4 * t + 2], e1[4 * t + 3]};
      // Dense nontemporal stores: 64 lanes x float4 = contiguous 1 KB block.
      __builtin_nontemporal_store(pv0, (f4*)(arow0 + t * 256 + lane * 4));
      __builtin_nontemporal_store(pv1, (f4*)(arow1 + t * 256 + lane * 4));
#pragma unroll
      for (int c = 0; c < 4; ++c) {
        const int u = 4 * t + c;
        a00 = fmaf(e0[u], vreg[u].x, a00);
        a01 = fmaf(e0[u], vreg[u].y, a01);
        a02 = fmaf(e0[u], vreg[u].z, a02);
        a03 = fmaf(e0[u], vreg[u].w, a03);
        a10 = fmaf(e1[u], vreg[u].x, a10);
        a11 = fmaf(e1[u], vreg[u].y, a11);
        a12 = fmaf(e1[u], vreg[u].z, a12);
        a13 = fmaf(e1[u], vreg[u].w, a13);
      }
    }
    a00 = wred_sum(a00);
    a01 = wred_sum(a01);
    a02 = wred_sum(a02);
    a03 = wred_sum(a03);
    a10 = wred_sum(a10);
    a11 = wred_sum(a11);
    a12 = wred_sum(a12);
    a13 = wred_sum(a13);
    if (lane == 0) {
      *(float4*)(ctx + ((size_t)b * 1024 + i0) * 8 + h * 4) =
          make_float4(a00, a01, a02, a03);
      *(float4*)(ctx + ((size_t)b * 1024 + i1) * 8 + h * 4) =
          make_float4(a10, a11, a12, a13);
    }
  }
}

extern "C" void kernel_launch(void* const* d_in, const int* in_sizes, int n_in,
                              void* d_out, int out_size, void* d_ws,
                              size_t ws_size, hipStream_t stream) {
  (void)in_sizes; (void)n_in; (void)out_size; (void)ws_size;
  const float* q = (const float*)d_in[0];
  const float* k = (const float*)d_in[1];
  const float* v = (const float*)d_in[2];
  const float* wq = (const float*)d_in[3];
  const float* wk = (const float*)d_in[4];
  const float* wv = (const float*)d_in[5];
  const float* wd = (const float*)d_in[6];
  float* outp = (float*)d_out;  // [0, 262144): out; then attn (B,H,S,S)
  float* attn = outp + 262144;

  float* wsf = (float*)d_ws;
  float* qp = wsf;
  float* kp = qp + (size_t)NSAMP * 8;
  float* vp = kp + (size_t)NSAMP * 8;
  float* ctx = vp + (size_t)NSAMP * 8;  // concat layout [b,s,h*4+d]

  hipLaunchKernelGGL(mhaq_qproj3_kernel, dim3(1536), dim3(256), 0, stream, q,
                     k, v, wq, wk, wv, qp, kp, vp);
  hipLaunchKernelGGL(mhaq_attn_kernel, dim3(2048), dim3(256), 0, stream, qp,
                     kp, vp, ctx, attn);
  hipLaunchKernelGGL(mhaq_qproj1_kernel, dim3(512), dim3(256), 0, stream, ctx,
                     wd, outp);
}